// Round 3
// baseline (110.252 us; speedup 1.0000x reference)
//
#include <hip/hip_runtime.h>
#include <math.h>

// feat_gan loss on MI355X (gfx950).
// Shapes fixed by reference setup_inputs():
//   layer0: B=4, N0=4096, C0=64   (xyz [4,4096,3] f32, feat [4,64,4096] f32)
//   layer1: B=4, N1=1024, C1=128
// radius^2 = 1.0, nsample = 1 (first src point within radius; argmax-first).
//
// One wave (64 lanes) per query point. Ballot-scan 64 src points/iter; first
// set bit of __ballot = argmax-first index. For N(0,I3) data the per-chunk
// hit prob is ~99.5%, so chunk 0 of BOTH ball queries (att and self/bat) is
// prefetched in one parallel load round; fallback loops are the ~0.5% tail.
// Masked-out queries contribute exactly 0 (reference zeroes both groups).
// Each wave writes one double partial to d_ws (no LDS, no atomics, no
// __syncthreads in the hot kernel); kernel 2 reduces 20480 partials.

#define RAD2 1.0f

constexpr int B  = 4;
constexpr int N0 = 4096, C0 = 64;
constexpr int N1 = 1024, C1 = 128;
constexpr int W0 = B * N0;          // 16384 waves (queries) in layer0
constexpr int W1 = B * N1;          // 4096 in layer1
constexpr int WT = W0 + W1;         // 20480
constexpr int WPB  = 4;             // waves per 256-thread block
constexpr int NBLK = WT / WPB;      // 5120 blocks (clean layer split at 4096)

template<int C, int N, int LOGN>
__device__ __forceinline__ float query_loss_wave(
    const float* __restrict__ att_xyz,   // [B,N,3]
    const float* __restrict__ bat_xyz,   // [B,N,3]
    const float* __restrict__ att_feat,  // [B,C,N]
    const float* __restrict__ bat_feat,  // [B,C,N]
    int gq, int lane)
{
    const int b = gq >> LOGN;
    const int n = gq & (N - 1);
    const float* aq = att_xyz + (size_t)b * N * 3;
    const float* bq = bat_xyz + (size_t)b * N * 3;

    // query point (wave-uniform)
    const float qx = bq[n * 3 + 0];
    const float qy = bq[n * 3 + 1];
    const float qz = bq[n * 3 + 2];

    // chunk 0 of BOTH ball queries, issued in one load round
    const float dax = qx - aq[lane * 3 + 0];
    const float day = qy - aq[lane * 3 + 1];
    const float daz = qz - aq[lane * 3 + 2];
    const float dbx = qx - bq[lane * 3 + 0];
    const float dby = qy - bq[lane * 3 + 1];
    const float dbz = qz - bq[lane * 3 + 2];
    const unsigned long long balA = __ballot(dax * dax + day * day + daz * daz < RAD2);
    const unsigned long long balB = __ballot(dbx * dbx + dby * dby + dbz * dbz < RAD2);

    // --- att ball query: first m with d2 < 1 ---
    int att_idx = -1;
    if (balA) {
        att_idx = (int)__builtin_ctzll(balA);
    } else {
        for (int c0 = 64; c0 < N; c0 += 64) {
            const int m = c0 + lane;
            const float dx = qx - aq[m * 3 + 0];
            const float dy = qy - aq[m * 3 + 1];
            const float dz = qz - aq[m * 3 + 2];
            const unsigned long long bal = __ballot(dx * dx + dy * dy + dz * dz < RAD2);
            if (bal) { att_idx = c0 + (int)__builtin_ctzll(bal); break; }
        }
    }
    if (att_idx < 0) return 0.0f;          // mask=false -> exact zero contribution

    // --- bat (self) ball query: guaranteed hit at m == n ---
    int bat_idx = n;
    if (balB) {
        bat_idx = (int)__builtin_ctzll(balB);
    } else {                                // implies n >= 64
        for (int c0 = 64; c0 < N; c0 += 64) {
            const int m = c0 + lane;
            const float dx = qx - bq[m * 3 + 0];
            const float dy = qy - bq[m * 3 + 1];
            const float dz = qz - bq[m * 3 + 2];
            const unsigned long long bal = __ballot(dx * dx + dy * dy + dz * dz < RAD2);
            if (bal) { bat_idx = c0 + (int)__builtin_ctzll(bal); break; }
        }
    }

    // --- gather + squared diff: lanes 0-2 xyz, lane c feature channel c ---
    float part = 0.0f;
    if (lane < 3) {
        const float d = aq[att_idx * 3 + lane] - bq[bat_idx * 3 + lane];
        part = d * d;
    }
    const float* af = att_feat + (size_t)b * C * N;
    const float* bf = bat_feat + (size_t)b * C * N;
    #pragma unroll
    for (int c = lane; c < C; c += 64) {
        const float d = af[c * N + att_idx] - bf[c * N + bat_idx];
        part += d * d;
    }
    return part;
}

__global__ __launch_bounds__(256) void fg_fused_kernel(
    const float* __restrict__ att_xyz0, const float* __restrict__ bat_xyz0,
    const float* __restrict__ att_feat0, const float* __restrict__ bat_feat0,
    const float* __restrict__ att_xyz1, const float* __restrict__ bat_xyz1,
    const float* __restrict__ att_feat1, const float* __restrict__ bat_feat1,
    double* __restrict__ partials)       // [WT], one double per wave
{
    const int lane = threadIdx.x & 63;
    const int gw   = blockIdx.x * WPB + (threadIdx.x >> 6);

    float part;
    if (gw < W0)   // block-uniform branch (W0 % WPB == 0)
        part = query_loss_wave<C0, N0, 12>(att_xyz0, bat_xyz0, att_feat0,
                                           bat_feat0, gw, lane);
    else
        part = query_loss_wave<C1, N1, 10>(att_xyz1, bat_xyz1, att_feat1,
                                           bat_feat1, gw - W0, lane);

    // wave reduce (64 lanes), then one store per wave — no LDS, no barrier
    #pragma unroll
    for (int off = 32; off > 0; off >>= 1)
        part += __shfl_down(part, off);
    if (lane == 0) partials[gw] = (double)part;
}

__global__ __launch_bounds__(1024) void fg_finalize_kernel(
    const double* __restrict__ partials,
    float* __restrict__ out)
{
    const int t = threadIdx.x;
    double s0 = 0.0, s1 = 0.0;
    #pragma unroll 4
    for (int i = t; i < W0; i += 1024) s0 += partials[i];
    for (int i = W0 + t; i < WT; i += 1024) s1 += partials[i];

    #pragma unroll
    for (int off = 32; off > 0; off >>= 1) {
        s0 += __shfl_down(s0, off);
        s1 += __shfl_down(s1, off);
    }

    __shared__ double sh0[16], sh1[16];
    const int lane = t & 63, w = t >> 6;
    if (lane == 0) { sh0[w] = s0; sh1[w] = s1; }
    __syncthreads();
    if (t == 0) {
        double a0 = 0.0, a1 = 0.0;
        #pragma unroll
        for (int i = 0; i < 16; ++i) { a0 += sh0[i]; a1 += sh1[i]; }
        const double l0 = a0 * (1.0 / 1097728.0);   // 1/(4*4096*67)
        const double l1 = a1 * (1.0 / 536576.0);    // 1/(4*1024*131)
        double loss = 0.5 * (l0 + l1);
        if (isnan(loss)) loss = l1;   // reference: where(isnan, losses[-1], loss)
        out[0] = (float)loss;
    }
}

extern "C" void kernel_launch(void* const* d_in, const int* in_sizes, int n_in,
                              void* d_out, int out_size, void* d_ws, size_t ws_size,
                              hipStream_t stream) {
    // setup_inputs order:
    // 0 att_xyz0  1 att_xyz1  2 bat_xyz0  3 bat_xyz1
    // 4 att_feat0 5 att_feat1 6 bat_feat0 7 bat_feat1
    const float* att_xyz0  = (const float*)d_in[0];
    const float* att_xyz1  = (const float*)d_in[1];
    const float* bat_xyz0  = (const float*)d_in[2];
    const float* bat_xyz1  = (const float*)d_in[3];
    const float* att_feat0 = (const float*)d_in[4];
    const float* att_feat1 = (const float*)d_in[5];
    const float* bat_feat0 = (const float*)d_in[6];
    const float* bat_feat1 = (const float*)d_in[7];
    float* out = (float*)d_out;

    double* partials = (double*)d_ws;   // WT doubles = 160 KiB scratch

    fg_fused_kernel<<<NBLK, 256, 0, stream>>>(
        att_xyz0, bat_xyz0, att_feat0, bat_feat0,
        att_xyz1, bat_xyz1, att_feat1, bat_feat1, partials);

    fg_finalize_kernel<<<1, 1024, 0, stream>>>(partials, out);
}